// Round 11
// baseline (1481.433 us; speedup 1.0000x reference)
//
#include <hip/hip_runtime.h>
#include <hip/hip_fp16.h>
#include <math.h>

#define TPB 256
#define HB 512          // bucket array size (power of 2, >= nbuk)
#define BSH 10          // bucket shift: bucket = dst >> 10, 1024 dst per bucket
#define TILE 16384      // edges per tile (LDS-stageable: 64 KB)
#define SRCBITS 19      // N = 500000 < 2^19
#define SRCMASK ((1u << SRCBITS) - 1)
#define CAP 17408       // LDS csr-staging entries per half-bucket in buildD

// ---- fp16x4 pack/unpack for the gathered g vectors (4 MB total -> L2-resident) ----
__device__ inline unsigned pk2(float a, float b) {
    union { __half2 h2; unsigned u; } cv;
    cv.h2 = __halves2half2(__float2half_rn(a), __float2half_rn(b));
    return cv.u;
}
__device__ inline float2 upk2(unsigned u) {
    union { unsigned u; __half2 h2; } cv; cv.u = u;
    return __half22float2(cv.h2);
}
// monotonic float<->uint encoding for atomicMax
__device__ inline unsigned encf(float x) {
    unsigned u = __float_as_uint(x);
    return (u & 0x80000000u) ? ~u : (u | 0x80000000u);
}
__device__ inline float decf(unsigned e) {
    unsigned u = (e & 0x80000000u) ? (e & 0x7FFFFFFFu) : ~e;
    return __uint_as_float(u);
}

// ---------------- CSR build: tile-bucketed counting sort ----------------

__global__ void histA_kernel(const int* __restrict__ dst, int* __restrict__ tileHist, int E) {
    __shared__ int h[HB];
    int t = threadIdx.x;
    for (int i = t; i < HB; i += TPB) h[i] = 0;
    __syncthreads();
    int base = blockIdx.x * TILE;
#pragma unroll
    for (int k = 0; k < TILE / (TPB * 4); k++) {
        int e = base + (k * TPB + t) * 4;
        if (e < E) {  // E % 4 == 0
            int4 d = *(const int4*)(dst + e);
            atomicAdd(&h[((unsigned)d.x) >> BSH], 1);
            atomicAdd(&h[((unsigned)d.y) >> BSH], 1);
            atomicAdd(&h[((unsigned)d.z) >> BSH], 1);
            atomicAdd(&h[((unsigned)d.w) >> BSH], 1);
        }
    }
    __syncthreads();
    int* out = tileHist + (size_t)blockIdx.x * HB;
    for (int i = t; i < HB; i += TPB) out[i] = h[i];
}

__global__ void btot_kernel(const int* __restrict__ tileHist, int* __restrict__ totals, int nTiles) {
    __shared__ int sh[TPB];
    int b = blockIdx.x, t = threadIdx.x;
    int s = 0;
    for (int i = t; i < nTiles; i += TPB) s += tileHist[(size_t)i * HB + b];
    sh[t] = s; __syncthreads();
    for (int d = TPB / 2; d > 0; d >>= 1) { if (t < d) sh[t] += sh[t + d]; __syncthreads(); }
    if (t == 0) totals[b] = sh[0];
}

__global__ void bscan_kernel(const int* __restrict__ totals, int* __restrict__ bucketStart) {
    __shared__ int sh[TPB];
    int t = threadIdx.x;
    int v0 = totals[t * 2], v1 = totals[t * 2 + 1];
    int s = v0 + v1;
    sh[t] = s; __syncthreads();
    for (int d = 1; d < TPB; d <<= 1) {
        int x = (t >= d) ? sh[t - d] : 0; __syncthreads();
        sh[t] += x; __syncthreads();
    }
    int excl = sh[t] - s;
    bucketStart[t * 2] = excl;
    bucketStart[t * 2 + 1] = excl + v0;
    if (t == TPB - 1) bucketStart[HB] = sh[TPB - 1];
}

__global__ void tbase_kernel(const int* __restrict__ tileHist, const int* __restrict__ bucketStart,
                             int* __restrict__ tileBase, int nTiles) {
    __shared__ int sh[TPB];
    int b = blockIdx.x, t = threadIdx.x;
    const int CH = 8;  // supports nTiles <= 2048 (977 here)
    int pre[CH]; int s = 0;
#pragma unroll
    for (int k = 0; k < CH; k++) {
        int i = t * CH + k;
        int v = (i < nTiles) ? tileHist[(size_t)i * HB + b] : 0;
        pre[k] = s; s += v;
    }
    sh[t] = s; __syncthreads();
    for (int d = 1; d < TPB; d <<= 1) {
        int x = (t >= d) ? sh[t - d] : 0; __syncthreads();
        sh[t] += x; __syncthreads();
    }
    int excl = sh[t] - s;
    int bs = bucketStart[b];
#pragma unroll
    for (int k = 0; k < CH; k++) {
        int i = t * CH + k;
        if (i < nTiles) tileBase[(size_t)i * HB + b] = bs + excl + pre[k];
    }
}

// C: LDS-staged tile sort. Histogram -> scan -> scatter into 64KB LDS stage ->
// per-bucket contiguous burst writeout (full-line merges, kills 5.5x write amp).
__global__ __launch_bounds__(TPB) void scatterC_kernel(
        const int* __restrict__ src, const int* __restrict__ dst,
        const int* __restrict__ tileBase, unsigned* __restrict__ bucketed, int E) {
    __shared__ int h[HB];
    __shared__ int hstart[HB];
    __shared__ int loc[HB];
    __shared__ int sh[TPB];
    __shared__ unsigned stage[TILE];  // 64 KB
    int t = threadIdx.x;
    for (int i = t; i < HB; i += TPB) h[i] = 0;
    __syncthreads();
    int base = blockIdx.x * TILE;
    // pass 1: local histogram of dst buckets
#pragma unroll
    for (int k = 0; k < TILE / (TPB * 4); k++) {
        int e = base + (k * TPB + t) * 4;
        if (e < E) {
            int4 d4 = *(const int4*)(dst + e);
            atomicAdd(&h[((unsigned)d4.x) >> BSH], 1);
            atomicAdd(&h[((unsigned)d4.y) >> BSH], 1);
            atomicAdd(&h[((unsigned)d4.z) >> BSH], 1);
            atomicAdd(&h[((unsigned)d4.w) >> BSH], 1);
        }
    }
    __syncthreads();
    // scan (HB = 2*TPB)
    int v0 = h[t * 2], v1 = h[t * 2 + 1];
    int s = v0 + v1;
    sh[t] = s; __syncthreads();
    for (int d = 1; d < TPB; d <<= 1) {
        int x = (t >= d) ? sh[t - d] : 0; __syncthreads();
        sh[t] += x; __syncthreads();
    }
    int excl = sh[t] - s;
    hstart[t * 2] = excl;         loc[t * 2] = excl;
    hstart[t * 2 + 1] = excl + v0; loc[t * 2 + 1] = excl + v0;
    __syncthreads();
    // pass 2: scatter packed entries into LDS stage
#pragma unroll
    for (int k = 0; k < TILE / (TPB * 4); k++) {
        int e = base + (k * TPB + t) * 4;
        if (e < E) {
            int4 s4 = *(const int4*)(src + e);
            int4 d4 = *(const int4*)(dst + e);
            int b0 = ((unsigned)d4.x) >> BSH;
            int p0 = atomicAdd(&loc[b0], 1);
            stage[p0] = ((unsigned)s4.x) | ((((unsigned)d4.x) & ((1u << BSH) - 1)) << SRCBITS);
            int b1 = ((unsigned)d4.y) >> BSH;
            int p1 = atomicAdd(&loc[b1], 1);
            stage[p1] = ((unsigned)s4.y) | ((((unsigned)d4.y) & ((1u << BSH) - 1)) << SRCBITS);
            int b2 = ((unsigned)d4.z) >> BSH;
            int p2 = atomicAdd(&loc[b2], 1);
            stage[p2] = ((unsigned)s4.z) | ((((unsigned)d4.z) & ((1u << BSH) - 1)) << SRCBITS);
            int b3 = ((unsigned)d4.w) >> BSH;
            int p3 = atomicAdd(&loc[b3], 1);
            stage[p3] = ((unsigned)s4.w) | ((((unsigned)d4.w) & ((1u << BSH) - 1)) << SRCBITS);
        }
    }
    __syncthreads();
    // writeout: wave-per-bucket contiguous bursts
    const int* tb = tileBase + (size_t)blockIdx.x * HB;
    int wave = t >> 6, lane = t & 63;
    for (int b = wave; b < HB; b += 4) {
        int sb = hstart[b], eb = loc[b];
        int gb = tb[b];
        for (int i = sb + lane; i < eb; i += 64)
            bucketed[gb + (i - sb)] = stage[i];
    }
}

// D: per HALF-bucket (512 dsts). Histogram -> scan -> scatter into LDS stage ->
// coalesced linear writeout of csr.
__global__ __launch_bounds__(TPB) void buildD_kernel(
        const unsigned* __restrict__ bucketed, const int* __restrict__ bucketStart,
        int* __restrict__ csr, int* __restrict__ off, float* __restrict__ dis,
        int N, int E, int nbuk) {
    const int DR = 512;
    __shared__ int h[DR];
    __shared__ int loc[DR];
    __shared__ int sh[TPB];
    __shared__ int totLow;
    __shared__ int stage[CAP];
    int blk = blockIdx.x;
    int b = blk >> 1, half = blk & 1;
    int t = threadIdx.x;
    int p0 = bucketStart[b], p1 = bucketStart[b + 1];
    for (int i = t; i < DR; i += TPB) h[i] = 0;
    if (t == 0) totLow = 0;
    __syncthreads();

    int aBeg = (p0 + 3) & ~3; if (aBeg > p1) aBeg = p1;
    int aEnd = p1 & ~3;        if (aEnd < aBeg) aEnd = aBeg;
    int lowCnt = 0;
    // pass 1: histogram of our half (count low half too if half==1)
    for (int p = p0 + t; p < aBeg; p += TPB) {
        int j = (int)(bucketed[p] >> SRCBITS);
        if ((j >> 9) == half) atomicAdd(&h[j & 511], 1);
        else if (half) lowCnt++;
    }
    for (int p = aBeg + t * 4; p < aEnd; p += TPB * 4) {
        uint4 v4 = *(const uint4*)(bucketed + p);
        unsigned vv[4] = {v4.x, v4.y, v4.z, v4.w};
#pragma unroll
        for (int q = 0; q < 4; q++) {
            int j = (int)(vv[q] >> SRCBITS);
            if ((j >> 9) == half) atomicAdd(&h[j & 511], 1);
            else if (half) lowCnt++;
        }
    }
    for (int p = aEnd + t; p < p1; p += TPB) {
        int j = (int)(bucketed[p] >> SRCBITS);
        if ((j >> 9) == half) atomicAdd(&h[j & 511], 1);
        else if (half) lowCnt++;
    }
    if (half && lowCnt) atomicAdd(&totLow, lowCnt);
    __syncthreads();

    // scan h (DR=512, 2 per thread)
    int v0 = h[t * 2], v1 = h[t * 2 + 1];
    int s = v0 + v1;
    sh[t] = s; __syncthreads();
    for (int d = 1; d < TPB; d <<= 1) {
        int x = (t >= d) ? sh[t - d] : 0; __syncthreads();
        sh[t] += x; __syncthreads();
    }
    int excl = sh[t] - s;
    int base = p0 + (half ? totLow : 0);
    int dstBase = (b << BSH) + (half << 9);
    {
        int j0 = t * 2, j1 = j0 + 1;
        loc[j0] = excl;
        loc[j1] = excl + v0;
        int d0 = dstBase + j0, d1 = dstBase + j1;
        if (d0 < N) { off[d0] = base + excl;      dis[d0] = rsqrtf((float)(v0 + 1)); }
        if (d1 < N) { off[d1] = base + excl + v0; dis[d1] = rsqrtf((float)(v1 + 1)); }
    }
    if (b == nbuk - 1 && half == 1 && t == 0) off[N] = E;
    int cnt = sh[TPB - 1];
    __syncthreads();

    // pass 2: scatter our half's srcs into LDS stage at local positions
    for (int p = p0 + t; p < aBeg; p += TPB) {
        unsigned v = bucketed[p];
        int j = (int)(v >> SRCBITS);
        if ((j >> 9) == half) {
            int pos = atomicAdd(&loc[j & 511], 1);
            int sv = (int)(v & SRCMASK);
            if (pos < CAP) stage[pos] = sv; else csr[base + pos] = sv;
        }
    }
    for (int p = aBeg + t * 4; p < aEnd; p += TPB * 4) {
        uint4 v4 = *(const uint4*)(bucketed + p);
        unsigned vv[4] = {v4.x, v4.y, v4.z, v4.w};
#pragma unroll
        for (int q = 0; q < 4; q++) {
            int j = (int)(vv[q] >> SRCBITS);
            if ((j >> 9) == half) {
                int pos = atomicAdd(&loc[j & 511], 1);
                int sv = (int)(vv[q] & SRCMASK);
                if (pos < CAP) stage[pos] = sv; else csr[base + pos] = sv;
            }
        }
    }
    for (int p = aEnd + t; p < p1; p += TPB) {
        unsigned v = bucketed[p];
        int j = (int)(v >> SRCBITS);
        if ((j >> 9) == half) {
            int pos = atomicAdd(&loc[j & 511], 1);
            int sv = (int)(v & SRCMASK);
            if (pos < CAP) stage[pos] = sv; else csr[base + pos] = sv;
        }
    }
    __syncthreads();
    // coalesced linear writeout
    int c = cnt < CAP ? cnt : CAP;
    for (int i = t; i < c; i += TPB) csr[base + i] = stage[i];
}

// ---------------- conv layers ----------------

// g0[v] = fp16( dis[v] * (x[v] @ W0) )
__global__ void g0_kernel(const float* __restrict__ x, const float* __restrict__ W0,
                          const float* __restrict__ dis, uint2* __restrict__ g, int N) {
    __shared__ float W[64];
    int t = threadIdx.x;
    if (t < 64) W[t] = W0[t];
    __syncthreads();
    int v = blockIdx.x * blockDim.x + t;
    if (v >= N) return;
    const float4* xp = (const float4*)(x + (size_t)v * 16);
    float o0 = 0.f, o1 = 0.f, o2 = 0.f, o3 = 0.f;
#pragma unroll
    for (int q = 0; q < 4; q++) {
        float4 xv = xp[q];
        float xk[4] = {xv.x, xv.y, xv.z, xv.w};
#pragma unroll
        for (int r = 0; r < 4; r++) {
            int k = q * 4 + r;
            o0 += xk[r] * W[k * 4 + 0];
            o1 += xk[r] * W[k * 4 + 1];
            o2 += xk[r] * W[k * 4 + 2];
            o3 += xk[r] * W[k * 4 + 3];
        }
    }
    float dv = dis[v];
    g[v] = make_uint2(pk2(dv * o0, dv * o1), pk2(dv * o2, dv * o3));
}

// fused: gather-agg (4 lanes/node, 2x unrolled, nt csr loads) + next-layer g + pooling
__global__ void agg_kernel(const int* __restrict__ off, const int* __restrict__ csr,
                           const uint2* __restrict__ gin, const float* __restrict__ dis,
                           const int* __restrict__ batch,
                           const float* __restrict__ bias, const float* __restrict__ Wn,
                           uint2* __restrict__ gout,
                           unsigned* __restrict__ pmax, float* __restrict__ psum,
                           int L, int N) {
    __shared__ float hx[64], hy[64], hz[64], hw[64];
    __shared__ int gid[64];
    int t = threadIdx.x;
    int lane = t & 3;
    int slot = t >> 2;
    int v = blockIdx.x * 64 + slot;
    bool valid = v < N;
    float sx = 0.f, sy = 0.f, sz = 0.f, sw = 0.f;
    float tx = 0.f, ty = 0.f, tz = 0.f, tw = 0.f;
    if (valid) {
        int p0 = off[v], p1 = off[v + 1];
        if (lane == 0) {
            uint2 r = gin[v];  // self loop
            float2 a = upk2(r.x), b = upk2(r.y);
            sx = a.x; sy = a.y; sz = b.x; sw = b.y;
        }
        int p = p0 + lane;
        for (; p + 4 < p1; p += 8) {
            // nt loads: csr streams once per layer -- keep it out of L2 so the
            // 4MB g gather table stays resident
            int i0 = __builtin_nontemporal_load(csr + p);
            int i1 = __builtin_nontemporal_load(csr + p + 4);
            uint2 r0 = gin[i0];
            uint2 r1 = gin[i1];
            float2 a0 = upk2(r0.x), b0 = upk2(r0.y);
            float2 a1 = upk2(r1.x), b1 = upk2(r1.y);
            sx += a0.x; sy += a0.y; sz += b0.x; sw += b0.y;
            tx += a1.x; ty += a1.y; tz += b1.x; tw += b1.y;
        }
        if (p < p1) {
            int i0 = __builtin_nontemporal_load(csr + p);
            uint2 r = gin[i0];
            float2 a = upk2(r.x), b = upk2(r.y);
            sx += a.x; sy += a.y; sz += b.x; sw += b.y;
        }
        sx += tx; sy += ty; sz += tz; sw += tw;
    }
    sx += __shfl_xor(sx, 1); sy += __shfl_xor(sy, 1); sz += __shfl_xor(sz, 1); sw += __shfl_xor(sw, 1);
    sx += __shfl_xor(sx, 2); sy += __shfl_xor(sy, 2); sz += __shfl_xor(sz, 2); sw += __shfl_xor(sw, 2);
    if (lane == 0) {
        if (valid) {
            float dv = dis[v];
            float h0 = dv * sx + bias[0];
            float h1 = dv * sy + bias[1];
            float h2 = dv * sz + bias[2];
            float h3 = dv * sw + bias[3];
            hx[slot] = h0; hy[slot] = h1; hz[slot] = h2; hw[slot] = h3;
            gid[slot] = batch[v];
            if (Wn) {
                float o0 = h0 * Wn[0] + h1 * Wn[4] + h2 * Wn[8]  + h3 * Wn[12];
                float o1 = h0 * Wn[1] + h1 * Wn[5] + h2 * Wn[9]  + h3 * Wn[13];
                float o2 = h0 * Wn[2] + h1 * Wn[6] + h2 * Wn[10] + h3 * Wn[14];
                float o3 = h0 * Wn[3] + h1 * Wn[7] + h2 * Wn[11] + h3 * Wn[15];
                gout[v] = make_uint2(pk2(dv * o0, dv * o1), pk2(dv * o2, dv * o3));
            }
        } else {
            gid[slot] = -1;
        }
    }
    __syncthreads();
    // segment heads reduce their graph's slice of this block and push atomics
    if (t < 64) {
        int g = gid[t];
        if (g >= 0 && (t == 0 || gid[t - 1] != g)) {
            float m0 = -INFINITY, m1 = -INFINITY, m2 = -INFINITY, m3 = -INFINITY;
            float s0 = 0.f, s1 = 0.f, s2 = 0.f, s3 = 0.f;
            for (int i = t; i < 64 && gid[i] == g; i++) {
                m0 = fmaxf(m0, hx[i]); s0 += hx[i];
                m1 = fmaxf(m1, hy[i]); s1 += hy[i];
                m2 = fmaxf(m2, hz[i]); s2 += hz[i];
                m3 = fmaxf(m3, hw[i]); s3 += hw[i];
            }
            unsigned* pm = pmax + (size_t)g * 28 + L * 4;
            float*    ps = psum + (size_t)g * 28 + L * 4;
            atomicMax(&pm[0], encf(m0)); atomicMax(&pm[1], encf(m1));
            atomicMax(&pm[2], encf(m2)); atomicMax(&pm[3], encf(m3));
            atomicAdd(&ps[0], s0); atomicAdd(&ps[1], s1);
            atomicAdd(&ps[2], s2); atomicAdd(&ps[3], s3);
        }
    }
}

// ---------------- graph bounds ----------------

__global__ void bounds_kernel(const int* __restrict__ batch, int* __restrict__ start,
                              int N, int ng) {
    int g = blockIdx.x * blockDim.x + threadIdx.x;
    if (g > ng) return;
    if (g == ng) { start[ng] = N; return; }
    int lo = 0, hi = N;
    while (lo < hi) {
        int mid = (lo + hi) >> 1;
        if (batch[mid] < g) lo = mid + 1; else hi = mid;
    }
    start[g] = lo;
}

// ---------------- MLP head ----------------

__global__ void mlp_kernel(const unsigned* __restrict__ pmax, const float* __restrict__ psum,
                           const int* __restrict__ start,
                           const float* __restrict__ Wout, const float* __restrict__ bout,
                           const float* __restrict__ Wout2, const float* __restrict__ bout2,
                           float* __restrict__ out, int ng) {
    __shared__ float hc[56];
    __shared__ float zz[56];
    int gph = blockIdx.x;
    int t = threadIdx.x;
    if (t < 56) {
        int L = t >> 3, k = t & 7;
        size_t base = (size_t)gph * 28 + L * 4;
        float val;
        if (k < 4) {
            val = decf(pmax[base + k]);
        } else {
            int cnt = start[gph + 1] - start[gph];
            float inv = 1.0f / (float)(cnt > 0 ? cnt : 1);
            val = psum[base + (k - 4)] * inv;
        }
        hc[t] = val;
    }
    __syncthreads();
    if (t < 56) {
        float acc = bout[t];
        for (int k = 0; k < 56; k++) acc += hc[k] * Wout[k * 56 + t];
        zz[t] = fmaxf(acc, 0.f);
    }
    __syncthreads();
    float val = (t < 56) ? zz[t] * Wout2[t] : 0.f;
#pragma unroll
    for (int d = 32; d > 0; d >>= 1) val += __shfl_down(val, d, 64);
    if (t == 0) {
        float logit = val + bout2[0];
        out[gph] = 1.f / (1.f + expf(-logit));
        out[ng + gph] = logit;
    }
}

// ---------------- launch ----------------

extern "C" void kernel_launch(void* const* d_in, const int* in_sizes, int n_in,
                              void* d_out, int out_size, void* d_ws, size_t ws_size,
                              hipStream_t stream) {
    const float* x     = (const float*)d_in[0];
    const int*   ei    = (const int*)d_in[1];
    const int*   batch = (const int*)d_in[2];
    const float* W0    = (const float*)d_in[4];
    const float* b0    = (const float*)d_in[5];
    const float* Wc    = (const float*)d_in[6];
    const float* bc    = (const float*)d_in[7];
    const float* Wout  = (const float*)d_in[8];
    const float* bout  = (const float*)d_in[9];
    const float* Wout2 = (const float*)d_in[10];
    const float* bout2 = (const float*)d_in[11];

    const int N  = in_sizes[0] / 16;
    const int E  = in_sizes[1] / 2;
    const int ng = 1024;
    const int* srcp = ei;
    const int* dstp = ei + E;
    const int nTiles = (E + TILE - 1) / TILE;        // 977, <= 2048
    const int nbuk   = (N + (1 << BSH) - 1) >> BSH;  // 489

    char* w = (char*)d_ws;
    auto alloc = [&](size_t bytes) -> char* {
        char* p = w;
        w += (bytes + 255) & ~(size_t)255;
        return p;
    };
    int*      csr         = (int*)alloc((size_t)E * 4);
    unsigned* bucketed    = (unsigned*)alloc((size_t)E * 4);
    int*      tileHist    = (int*)alloc((size_t)nTiles * HB * 4);
    int*      tileBase    = (int*)alloc((size_t)nTiles * HB * 4);
    int*      totals      = (int*)alloc((size_t)HB * 4);
    int*      bucketStart = (int*)alloc((size_t)(HB + 1) * 4);
    int*      off         = (int*)alloc((size_t)(N + 1) * 4);
    float*    dis         = (float*)alloc((size_t)N * 4);
    int*      start       = (int*)alloc((size_t)(ng + 1) * 4);
    unsigned* pmax        = (unsigned*)alloc((size_t)ng * 28 * 4);
    float*    psum        = (float*)alloc((size_t)ng * 28 * 4);
    // reuse bucketed region (64MB) for the two fp16x4 g buffers (4MB each) after buildD
    uint2*    gA = (uint2*)bucketed;
    uint2*    gB = gA + N;

    // ---- build CSR ----
    histA_kernel<<<nTiles, TPB, 0, stream>>>(dstp, tileHist, E);
    btot_kernel<<<HB, TPB, 0, stream>>>(tileHist, totals, nTiles);
    bscan_kernel<<<1, TPB, 0, stream>>>(totals, bucketStart);
    tbase_kernel<<<HB, TPB, 0, stream>>>(tileHist, bucketStart, tileBase, nTiles);
    scatterC_kernel<<<nTiles, TPB, 0, stream>>>(srcp, dstp, tileBase, bucketed, E);
    buildD_kernel<<<nbuk * 2, TPB, 0, stream>>>(bucketed, bucketStart, csr, off, dis, N, E, nbuk);
    bounds_kernel<<<(ng + 1 + TPB - 1) / TPB, TPB, 0, stream>>>(batch, start, N, ng);
    hipMemsetAsync(pmax, 0, (size_t)ng * 28 * 4, stream);
    hipMemsetAsync(psum, 0, (size_t)ng * 28 * 4, stream);

    // ---- layers (pooling fused into agg) ----
    const int gbN = (N + TPB - 1) / TPB;
    g0_kernel<<<gbN, TPB, 0, stream>>>(x, W0, dis, gA, N);

    const int gbAgg = (N + 63) / 64;
    uint2* gin = gA;
    uint2* gout = gB;
    for (int L = 0; L < 7; ++L) {
        const float* bias = (L == 0) ? b0 : bc + (size_t)(L - 1) * 4;
        const float* Wn   = (L < 6) ? Wc + (size_t)L * 16 : nullptr;
        agg_kernel<<<gbAgg, TPB, 0, stream>>>(off, csr, gin, dis, batch, bias, Wn,
                                              gout, pmax, psum, L, N);
        uint2* tmp = gin; gin = gout; gout = tmp;
    }

    mlp_kernel<<<ng, 64, 0, stream>>>(pmax, psum, start, Wout, bout, Wout2, bout2,
                                      (float*)d_out, ng);
}

// Round 12
// 1154.634 us; speedup vs baseline: 1.2830x; 1.2830x over previous
//
#include <hip/hip_runtime.h>
#include <hip/hip_fp16.h>
#include <math.h>

#define TPB 256
#define HB 512          // bucket array size (power of 2, >= nbuk)
#define BSH 10          // bucket shift: bucket = dst >> 10, 1024 dst per bucket
#define TILE 16384      // edges per tile (LDS-stageable: 64 KB)
#define SRCBITS 19      // N = 500000 < 2^19
#define SRCMASK ((1u << SRCBITS) - 1)
#define CAP 17408       // LDS csr-staging entries per half-bucket in buildD

// ---- fp16x4 pack/unpack for the gathered g vectors (4 MB total -> L2-resident) ----
__device__ inline unsigned pk2(float a, float b) {
    union { __half2 h2; unsigned u; } cv;
    cv.h2 = __halves2half2(__float2half_rn(a), __float2half_rn(b));
    return cv.u;
}
__device__ inline float2 upk2(unsigned u) {
    union { unsigned u; __half2 h2; } cv; cv.u = u;
    return __half22float2(cv.h2);
}
// monotonic float<->uint encoding for atomicMax
__device__ inline unsigned encf(float x) {
    unsigned u = __float_as_uint(x);
    return (u & 0x80000000u) ? ~u : (u | 0x80000000u);
}
__device__ inline float decf(unsigned e) {
    unsigned u = (e & 0x80000000u) ? (e & 0x7FFFFFFFu) : ~e;
    return __uint_as_float(u);
}

// ---------------- CSR build: tile-bucketed counting sort ----------------

__global__ void histA_kernel(const int* __restrict__ dst, int* __restrict__ tileHist, int E) {
    __shared__ int h[HB];
    int t = threadIdx.x;
    for (int i = t; i < HB; i += TPB) h[i] = 0;
    __syncthreads();
    int base = blockIdx.x * TILE;
#pragma unroll
    for (int k = 0; k < TILE / (TPB * 4); k++) {
        int e = base + (k * TPB + t) * 4;
        if (e < E) {  // E % 4 == 0
            int4 d = *(const int4*)(dst + e);
            atomicAdd(&h[((unsigned)d.x) >> BSH], 1);
            atomicAdd(&h[((unsigned)d.y) >> BSH], 1);
            atomicAdd(&h[((unsigned)d.z) >> BSH], 1);
            atomicAdd(&h[((unsigned)d.w) >> BSH], 1);
        }
    }
    __syncthreads();
    int* out = tileHist + (size_t)blockIdx.x * HB;
    for (int i = t; i < HB; i += TPB) out[i] = h[i];
}

__global__ void btot_kernel(const int* __restrict__ tileHist, int* __restrict__ totals, int nTiles) {
    __shared__ int sh[TPB];
    int b = blockIdx.x, t = threadIdx.x;
    int s = 0;
    for (int i = t; i < nTiles; i += TPB) s += tileHist[(size_t)i * HB + b];
    sh[t] = s; __syncthreads();
    for (int d = TPB / 2; d > 0; d >>= 1) { if (t < d) sh[t] += sh[t + d]; __syncthreads(); }
    if (t == 0) totals[b] = sh[0];
}

__global__ void bscan_kernel(const int* __restrict__ totals, int* __restrict__ bucketStart) {
    __shared__ int sh[TPB];
    int t = threadIdx.x;
    int v0 = totals[t * 2], v1 = totals[t * 2 + 1];
    int s = v0 + v1;
    sh[t] = s; __syncthreads();
    for (int d = 1; d < TPB; d <<= 1) {
        int x = (t >= d) ? sh[t - d] : 0; __syncthreads();
        sh[t] += x; __syncthreads();
    }
    int excl = sh[t] - s;
    bucketStart[t * 2] = excl;
    bucketStart[t * 2 + 1] = excl + v0;
    if (t == TPB - 1) bucketStart[HB] = sh[TPB - 1];
}

__global__ void tbase_kernel(const int* __restrict__ tileHist, const int* __restrict__ bucketStart,
                             int* __restrict__ tileBase, int nTiles) {
    __shared__ int sh[TPB];
    int b = blockIdx.x, t = threadIdx.x;
    const int CH = 8;  // supports nTiles <= 2048 (977 here)
    int pre[CH]; int s = 0;
#pragma unroll
    for (int k = 0; k < CH; k++) {
        int i = t * CH + k;
        int v = (i < nTiles) ? tileHist[(size_t)i * HB + b] : 0;
        pre[k] = s; s += v;
    }
    sh[t] = s; __syncthreads();
    for (int d = 1; d < TPB; d <<= 1) {
        int x = (t >= d) ? sh[t - d] : 0; __syncthreads();
        sh[t] += x; __syncthreads();
    }
    int excl = sh[t] - s;
    int bs = bucketStart[b];
#pragma unroll
    for (int k = 0; k < CH; k++) {
        int i = t * CH + k;
        if (i < nTiles) tileBase[(size_t)i * HB + b] = bs + excl + pre[k];
    }
}

// C: LDS-staged tile sort. Histogram -> scan -> scatter into 64KB LDS stage ->
// per-bucket contiguous burst writeout.
__global__ __launch_bounds__(TPB) void scatterC_kernel(
        const int* __restrict__ src, const int* __restrict__ dst,
        const int* __restrict__ tileBase, unsigned* __restrict__ bucketed, int E) {
    __shared__ int h[HB];
    __shared__ int hstart[HB];
    __shared__ int loc[HB];
    __shared__ int sh[TPB];
    __shared__ unsigned stage[TILE];  // 64 KB
    int t = threadIdx.x;
    for (int i = t; i < HB; i += TPB) h[i] = 0;
    __syncthreads();
    int base = blockIdx.x * TILE;
    // pass 1: local histogram of dst buckets
#pragma unroll
    for (int k = 0; k < TILE / (TPB * 4); k++) {
        int e = base + (k * TPB + t) * 4;
        if (e < E) {
            int4 d4 = *(const int4*)(dst + e);
            atomicAdd(&h[((unsigned)d4.x) >> BSH], 1);
            atomicAdd(&h[((unsigned)d4.y) >> BSH], 1);
            atomicAdd(&h[((unsigned)d4.z) >> BSH], 1);
            atomicAdd(&h[((unsigned)d4.w) >> BSH], 1);
        }
    }
    __syncthreads();
    // scan (HB = 2*TPB)
    int v0 = h[t * 2], v1 = h[t * 2 + 1];
    int s = v0 + v1;
    sh[t] = s; __syncthreads();
    for (int d = 1; d < TPB; d <<= 1) {
        int x = (t >= d) ? sh[t - d] : 0; __syncthreads();
        sh[t] += x; __syncthreads();
    }
    int excl = sh[t] - s;
    hstart[t * 2] = excl;          loc[t * 2] = excl;
    hstart[t * 2 + 1] = excl + v0; loc[t * 2 + 1] = excl + v0;
    __syncthreads();
    // pass 2: scatter packed entries into LDS stage
#pragma unroll
    for (int k = 0; k < TILE / (TPB * 4); k++) {
        int e = base + (k * TPB + t) * 4;
        if (e < E) {
            int4 s4 = *(const int4*)(src + e);
            int4 d4 = *(const int4*)(dst + e);
            int b0 = ((unsigned)d4.x) >> BSH;
            int p0 = atomicAdd(&loc[b0], 1);
            stage[p0] = ((unsigned)s4.x) | ((((unsigned)d4.x) & ((1u << BSH) - 1)) << SRCBITS);
            int b1 = ((unsigned)d4.y) >> BSH;
            int p1 = atomicAdd(&loc[b1], 1);
            stage[p1] = ((unsigned)s4.y) | ((((unsigned)d4.y) & ((1u << BSH) - 1)) << SRCBITS);
            int b2 = ((unsigned)d4.z) >> BSH;
            int p2 = atomicAdd(&loc[b2], 1);
            stage[p2] = ((unsigned)s4.z) | ((((unsigned)d4.z) & ((1u << BSH) - 1)) << SRCBITS);
            int b3 = ((unsigned)d4.w) >> BSH;
            int p3 = atomicAdd(&loc[b3], 1);
            stage[p3] = ((unsigned)s4.w) | ((((unsigned)d4.w) & ((1u << BSH) - 1)) << SRCBITS);
        }
    }
    __syncthreads();
    // writeout: wave-per-bucket contiguous bursts
    const int* tb = tileBase + (size_t)blockIdx.x * HB;
    int wave = t >> 6, lane = t & 63;
    for (int b = wave; b < HB; b += 4) {
        int sb = hstart[b], eb = loc[b];
        int gb = tb[b];
        for (int i = sb + lane; i < eb; i += 64)
            bucketed[gb + (i - sb)] = stage[i];
    }
}

// D: per HALF-bucket (512 dsts). Histogram -> scan -> scatter into LDS stage ->
// coalesced linear writeout of csr.
__global__ __launch_bounds__(TPB) void buildD_kernel(
        const unsigned* __restrict__ bucketed, const int* __restrict__ bucketStart,
        int* __restrict__ csr, int* __restrict__ off, float* __restrict__ dis,
        int N, int E, int nbuk) {
    const int DR = 512;
    __shared__ int h[DR];
    __shared__ int loc[DR];
    __shared__ int sh[TPB];
    __shared__ int totLow;
    __shared__ int stage[CAP];
    int blk = blockIdx.x;
    int b = blk >> 1, half = blk & 1;
    int t = threadIdx.x;
    int p0 = bucketStart[b], p1 = bucketStart[b + 1];
    for (int i = t; i < DR; i += TPB) h[i] = 0;
    if (t == 0) totLow = 0;
    __syncthreads();

    int aBeg = (p0 + 3) & ~3; if (aBeg > p1) aBeg = p1;
    int aEnd = p1 & ~3;        if (aEnd < aBeg) aEnd = aBeg;
    int lowCnt = 0;
    // pass 1: histogram of our half (count low half too if half==1)
    for (int p = p0 + t; p < aBeg; p += TPB) {
        int j = (int)(bucketed[p] >> SRCBITS);
        if ((j >> 9) == half) atomicAdd(&h[j & 511], 1);
        else if (half) lowCnt++;
    }
    for (int p = aBeg + t * 4; p < aEnd; p += TPB * 4) {
        uint4 v4 = *(const uint4*)(bucketed + p);
        unsigned vv[4] = {v4.x, v4.y, v4.z, v4.w};
#pragma unroll
        for (int q = 0; q < 4; q++) {
            int j = (int)(vv[q] >> SRCBITS);
            if ((j >> 9) == half) atomicAdd(&h[j & 511], 1);
            else if (half) lowCnt++;
        }
    }
    for (int p = aEnd + t; p < p1; p += TPB) {
        int j = (int)(bucketed[p] >> SRCBITS);
        if ((j >> 9) == half) atomicAdd(&h[j & 511], 1);
        else if (half) lowCnt++;
    }
    if (half && lowCnt) atomicAdd(&totLow, lowCnt);
    __syncthreads();

    // scan h (DR=512, 2 per thread)
    int v0 = h[t * 2], v1 = h[t * 2 + 1];
    int s = v0 + v1;
    sh[t] = s; __syncthreads();
    for (int d = 1; d < TPB; d <<= 1) {
        int x = (t >= d) ? sh[t - d] : 0; __syncthreads();
        sh[t] += x; __syncthreads();
    }
    int excl = sh[t] - s;
    int base = p0 + (half ? totLow : 0);
    int dstBase = (b << BSH) + (half << 9);
    {
        int j0 = t * 2, j1 = j0 + 1;
        loc[j0] = excl;
        loc[j1] = excl + v0;
        int d0 = dstBase + j0, d1 = dstBase + j1;
        if (d0 < N) { off[d0] = base + excl;      dis[d0] = rsqrtf((float)(v0 + 1)); }
        if (d1 < N) { off[d1] = base + excl + v0; dis[d1] = rsqrtf((float)(v1 + 1)); }
    }
    if (b == nbuk - 1 && half == 1 && t == 0) off[N] = E;
    int cnt = sh[TPB - 1];
    __syncthreads();

    // pass 2: scatter our half's srcs into LDS stage at local positions
    for (int p = p0 + t; p < aBeg; p += TPB) {
        unsigned v = bucketed[p];
        int j = (int)(v >> SRCBITS);
        if ((j >> 9) == half) {
            int pos = atomicAdd(&loc[j & 511], 1);
            int sv = (int)(v & SRCMASK);
            if (pos < CAP) stage[pos] = sv; else csr[base + pos] = sv;
        }
    }
    for (int p = aBeg + t * 4; p < aEnd; p += TPB * 4) {
        uint4 v4 = *(const uint4*)(bucketed + p);
        unsigned vv[4] = {v4.x, v4.y, v4.z, v4.w};
#pragma unroll
        for (int q = 0; q < 4; q++) {
            int j = (int)(vv[q] >> SRCBITS);
            if ((j >> 9) == half) {
                int pos = atomicAdd(&loc[j & 511], 1);
                int sv = (int)(vv[q] & SRCMASK);
                if (pos < CAP) stage[pos] = sv; else csr[base + pos] = sv;
            }
        }
    }
    for (int p = aEnd + t; p < p1; p += TPB) {
        unsigned v = bucketed[p];
        int j = (int)(v >> SRCBITS);
        if ((j >> 9) == half) {
            int pos = atomicAdd(&loc[j & 511], 1);
            int sv = (int)(v & SRCMASK);
            if (pos < CAP) stage[pos] = sv; else csr[base + pos] = sv;
        }
    }
    __syncthreads();
    // coalesced linear writeout
    int c = cnt < CAP ? cnt : CAP;
    for (int i = t; i < c; i += TPB) csr[base + i] = stage[i];
}

// ---------------- conv layers ----------------

// g0[v] = fp16( dis[v] * (x[v] @ W0) )
__global__ void g0_kernel(const float* __restrict__ x, const float* __restrict__ W0,
                          const float* __restrict__ dis, uint2* __restrict__ g, int N) {
    __shared__ float W[64];
    int t = threadIdx.x;
    if (t < 64) W[t] = W0[t];
    __syncthreads();
    int v = blockIdx.x * blockDim.x + t;
    if (v >= N) return;
    const float4* xp = (const float4*)(x + (size_t)v * 16);
    float o0 = 0.f, o1 = 0.f, o2 = 0.f, o3 = 0.f;
#pragma unroll
    for (int q = 0; q < 4; q++) {
        float4 xv = xp[q];
        float xk[4] = {xv.x, xv.y, xv.z, xv.w};
#pragma unroll
        for (int r = 0; r < 4; r++) {
            int k = q * 4 + r;
            o0 += xk[r] * W[k * 4 + 0];
            o1 += xk[r] * W[k * 4 + 1];
            o2 += xk[r] * W[k * 4 + 2];
            o3 += xk[r] * W[k * 4 + 3];
        }
    }
    float dv = dis[v];
    g[v] = make_uint2(pk2(dv * o0, dv * o1), pk2(dv * o2, dv * o3));
}

// fused: gather-agg (8 lanes/node, int4 csr loads -> 4 gathers in flight/lane)
//        + next-layer g + pooling partials
__global__ void agg_kernel(const int* __restrict__ off, const int* __restrict__ csr,
                           const uint2* __restrict__ gin, const float* __restrict__ dis,
                           const int* __restrict__ batch,
                           const float* __restrict__ bias, const float* __restrict__ Wn,
                           uint2* __restrict__ gout,
                           unsigned* __restrict__ pmax, float* __restrict__ psum,
                           int L, int N) {
    __shared__ float hx[32], hy[32], hz[32], hw[32];
    __shared__ int gid[32];
    int t = threadIdx.x;
    int lane = t & 7;
    int slot = t >> 3;
    int v = blockIdx.x * 32 + slot;
    bool valid = v < N;
    float sx = 0.f, sy = 0.f, sz = 0.f, sw = 0.f;
    if (valid) {
        int p0 = off[v], p1 = off[v + 1];
        if (lane == 0) {
            uint2 r = gin[v];  // self loop
            float2 a = upk2(r.x), b = upk2(r.y);
            sx = a.x; sy = a.y; sz = b.x; sw = b.y;
        }
        int aBeg = (p0 + 3) & ~3; if (aBeg > p1) aBeg = p1;
        int aEnd = p1 & ~3;        if (aEnd < aBeg) aEnd = aBeg;
        // scalar prologue (<=3) and epilogue (<=3), one per lane
        int pp = p0 + lane;
        if (pp < aBeg) {
            uint2 r = gin[csr[pp]];
            float2 a = upk2(r.x), b = upk2(r.y);
            sx += a.x; sy += a.y; sz += b.x; sw += b.y;
        }
        int pe = aEnd + lane;
        if (pe < p1) {
            uint2 r = gin[csr[pe]];
            float2 a = upk2(r.x), b = upk2(r.y);
            sx += a.x; sy += a.y; sz += b.x; sw += b.y;
        }
        // main: each lane loads int4 of csr (16B aligned) -> 4 independent gathers
        for (int p = aBeg + lane * 4; p < aEnd; p += 32) {
            int4 c = *(const int4*)(csr + p);
            uint2 r0 = gin[c.x];
            uint2 r1 = gin[c.y];
            uint2 r2 = gin[c.z];
            uint2 r3 = gin[c.w];
            float2 a0 = upk2(r0.x), b0 = upk2(r0.y);
            float2 a1 = upk2(r1.x), b1 = upk2(r1.y);
            float2 a2 = upk2(r2.x), b2 = upk2(r2.y);
            float2 a3 = upk2(r3.x), b3 = upk2(r3.y);
            sx += (a0.x + a1.x) + (a2.x + a3.x);
            sy += (a0.y + a1.y) + (a2.y + a3.y);
            sz += (b0.x + b1.x) + (b2.x + b3.x);
            sw += (b0.y + b1.y) + (b2.y + b3.y);
        }
    }
    sx += __shfl_xor(sx, 1); sy += __shfl_xor(sy, 1); sz += __shfl_xor(sz, 1); sw += __shfl_xor(sw, 1);
    sx += __shfl_xor(sx, 2); sy += __shfl_xor(sy, 2); sz += __shfl_xor(sz, 2); sw += __shfl_xor(sw, 2);
    sx += __shfl_xor(sx, 4); sy += __shfl_xor(sy, 4); sz += __shfl_xor(sz, 4); sw += __shfl_xor(sw, 4);
    if (lane == 0) {
        if (valid) {
            float dv = dis[v];
            float h0 = dv * sx + bias[0];
            float h1 = dv * sy + bias[1];
            float h2 = dv * sz + bias[2];
            float h3 = dv * sw + bias[3];
            hx[slot] = h0; hy[slot] = h1; hz[slot] = h2; hw[slot] = h3;
            gid[slot] = batch[v];
            if (Wn) {
                float o0 = h0 * Wn[0] + h1 * Wn[4] + h2 * Wn[8]  + h3 * Wn[12];
                float o1 = h0 * Wn[1] + h1 * Wn[5] + h2 * Wn[9]  + h3 * Wn[13];
                float o2 = h0 * Wn[2] + h1 * Wn[6] + h2 * Wn[10] + h3 * Wn[14];
                float o3 = h0 * Wn[3] + h1 * Wn[7] + h2 * Wn[11] + h3 * Wn[15];
                gout[v] = make_uint2(pk2(dv * o0, dv * o1), pk2(dv * o2, dv * o3));
            }
        } else {
            gid[slot] = -1;
        }
    }
    __syncthreads();
    // segment heads reduce their graph's slice of this block and push atomics
    if (t < 32) {
        int g = gid[t];
        if (g >= 0 && (t == 0 || gid[t - 1] != g)) {
            float m0 = -INFINITY, m1 = -INFINITY, m2 = -INFINITY, m3 = -INFINITY;
            float s0 = 0.f, s1 = 0.f, s2 = 0.f, s3 = 0.f;
            for (int i = t; i < 32 && gid[i] == g; i++) {
                m0 = fmaxf(m0, hx[i]); s0 += hx[i];
                m1 = fmaxf(m1, hy[i]); s1 += hy[i];
                m2 = fmaxf(m2, hz[i]); s2 += hz[i];
                m3 = fmaxf(m3, hw[i]); s3 += hw[i];
            }
            unsigned* pm = pmax + (size_t)g * 28 + L * 4;
            float*    ps = psum + (size_t)g * 28 + L * 4;
            atomicMax(&pm[0], encf(m0)); atomicMax(&pm[1], encf(m1));
            atomicMax(&pm[2], encf(m2)); atomicMax(&pm[3], encf(m3));
            atomicAdd(&ps[0], s0); atomicAdd(&ps[1], s1);
            atomicAdd(&ps[2], s2); atomicAdd(&ps[3], s3);
        }
    }
}

// ---------------- graph bounds ----------------

__global__ void bounds_kernel(const int* __restrict__ batch, int* __restrict__ start,
                              int N, int ng) {
    int g = blockIdx.x * blockDim.x + threadIdx.x;
    if (g > ng) return;
    if (g == ng) { start[ng] = N; return; }
    int lo = 0, hi = N;
    while (lo < hi) {
        int mid = (lo + hi) >> 1;
        if (batch[mid] < g) lo = mid + 1; else hi = mid;
    }
    start[g] = lo;
}

// ---------------- MLP head ----------------

__global__ void mlp_kernel(const unsigned* __restrict__ pmax, const float* __restrict__ psum,
                           const int* __restrict__ start,
                           const float* __restrict__ Wout, const float* __restrict__ bout,
                           const float* __restrict__ Wout2, const float* __restrict__ bout2,
                           float* __restrict__ out, int ng) {
    __shared__ float hc[56];
    __shared__ float zz[56];
    int gph = blockIdx.x;
    int t = threadIdx.x;
    if (t < 56) {
        int L = t >> 3, k = t & 7;
        size_t base = (size_t)gph * 28 + L * 4;
        float val;
        if (k < 4) {
            val = decf(pmax[base + k]);
        } else {
            int cnt = start[gph + 1] - start[gph];
            float inv = 1.0f / (float)(cnt > 0 ? cnt : 1);
            val = psum[base + (k - 4)] * inv;
        }
        hc[t] = val;
    }
    __syncthreads();
    if (t < 56) {
        float acc = bout[t];
        for (int k = 0; k < 56; k++) acc += hc[k] * Wout[k * 56 + t];
        zz[t] = fmaxf(acc, 0.f);
    }
    __syncthreads();
    float val = (t < 56) ? zz[t] * Wout2[t] : 0.f;
#pragma unroll
    for (int d = 32; d > 0; d >>= 1) val += __shfl_down(val, d, 64);
    if (t == 0) {
        float logit = val + bout2[0];
        out[gph] = 1.f / (1.f + expf(-logit));
        out[ng + gph] = logit;
    }
}

// ---------------- launch ----------------

extern "C" void kernel_launch(void* const* d_in, const int* in_sizes, int n_in,
                              void* d_out, int out_size, void* d_ws, size_t ws_size,
                              hipStream_t stream) {
    const float* x     = (const float*)d_in[0];
    const int*   ei    = (const int*)d_in[1];
    const int*   batch = (const int*)d_in[2];
    const float* W0    = (const float*)d_in[4];
    const float* b0    = (const float*)d_in[5];
    const float* Wc    = (const float*)d_in[6];
    const float* bc    = (const float*)d_in[7];
    const float* Wout  = (const float*)d_in[8];
    const float* bout  = (const float*)d_in[9];
    const float* Wout2 = (const float*)d_in[10];
    const float* bout2 = (const float*)d_in[11];

    const int N  = in_sizes[0] / 16;
    const int E  = in_sizes[1] / 2;
    const int ng = 1024;
    const int* srcp = ei;
    const int* dstp = ei + E;
    const int nTiles = (E + TILE - 1) / TILE;        // 977, <= 2048
    const int nbuk   = (N + (1 << BSH) - 1) >> BSH;  // 489

    char* w = (char*)d_ws;
    auto alloc = [&](size_t bytes) -> char* {
        char* p = w;
        w += (bytes + 255) & ~(size_t)255;
        return p;
    };
    int*      csr         = (int*)alloc((size_t)E * 4);
    unsigned* bucketed    = (unsigned*)alloc((size_t)E * 4);
    int*      tileHist    = (int*)alloc((size_t)nTiles * HB * 4);
    int*      tileBase    = (int*)alloc((size_t)nTiles * HB * 4);
    int*      totals      = (int*)alloc((size_t)HB * 4);
    int*      bucketStart = (int*)alloc((size_t)(HB + 1) * 4);
    int*      off         = (int*)alloc((size_t)(N + 1) * 4);
    float*    dis         = (float*)alloc((size_t)N * 4);
    int*      start       = (int*)alloc((size_t)(ng + 1) * 4);
    unsigned* pmax        = (unsigned*)alloc((size_t)ng * 28 * 4);
    float*    psum        = (float*)alloc((size_t)ng * 28 * 4);
    // reuse bucketed region (64MB) for the two fp16x4 g buffers (4MB each) after buildD
    uint2*    gA = (uint2*)bucketed;
    uint2*    gB = gA + N;

    // ---- build CSR ----
    histA_kernel<<<nTiles, TPB, 0, stream>>>(dstp, tileHist, E);
    btot_kernel<<<HB, TPB, 0, stream>>>(tileHist, totals, nTiles);
    bscan_kernel<<<1, TPB, 0, stream>>>(totals, bucketStart);
    tbase_kernel<<<HB, TPB, 0, stream>>>(tileHist, bucketStart, tileBase, nTiles);
    scatterC_kernel<<<nTiles, TPB, 0, stream>>>(srcp, dstp, tileBase, bucketed, E);
    buildD_kernel<<<nbuk * 2, TPB, 0, stream>>>(bucketed, bucketStart, csr, off, dis, N, E, nbuk);
    bounds_kernel<<<(ng + 1 + TPB - 1) / TPB, TPB, 0, stream>>>(batch, start, N, ng);
    hipMemsetAsync(pmax, 0, (size_t)ng * 28 * 4, stream);
    hipMemsetAsync(psum, 0, (size_t)ng * 28 * 4, stream);

    // ---- layers (pooling fused into agg) ----
    const int gbN = (N + TPB - 1) / TPB;
    g0_kernel<<<gbN, TPB, 0, stream>>>(x, W0, dis, gA, N);

    const int gbAgg = (N + 31) / 32;
    uint2* gin = gA;
    uint2* gout = gB;
    for (int L = 0; L < 7; ++L) {
        const float* bias = (L == 0) ? b0 : bc + (size_t)(L - 1) * 4;
        const float* Wn   = (L < 6) ? Wc + (size_t)L * 16 : nullptr;
        agg_kernel<<<gbAgg, TPB, 0, stream>>>(off, csr, gin, dis, batch, bias, Wn,
                                              gout, pmax, psum, L, N);
        uint2* tmp = gin; gin = gout; gout = tmp;
    }

    mlp_kernel<<<ng, 64, 0, stream>>>(pmax, psum, start, Wout, bout, Wout2, bout2,
                                      (float*)d_out, ng);
}